// Round 2
// baseline (189.202 us; speedup 1.0000x reference)
//
#include <hip/hip_runtime.h>

// ReflexPolicy fused kernel v2: b128-packed LDS, DPP softmax, double-buffered staging.
// 512 blocks x 256 threads, BT=16 rows/block, 2 rows per thread.

#define TOBS 64
#define TACT 32
#define TLAT 25
#define TH   5
#define TB   8192
#define BT   16
#define OCH  4          // obs per chunk
#define NCH  16         // 64/OCH chunks
#define ATS  28         // At stride (words): 25 data + 3 pad, 16B-aligned
#define WTS  20         // Wt stride (words): 16 data + 4 pad, 16B-aligned
#define HSTR 68         // row stride for obs/h tiles (16B-aligned)

// x + dpp_moved(x); ctrl must be a literal.
#define DPP_ADD(x, ctrl) \
  ((x) + __builtin_bit_cast(float, __builtin_amdgcn_update_dpp( \
      0, __builtin_bit_cast(int, (x)), (ctrl), 0xF, 0xF, true)))

__device__ __forceinline__ float halfwave_sum(float x) {
    x = DPP_ADD(x, 0xB1);   // quad_perm [1,0,3,2]  == xor1
    x = DPP_ADD(x, 0x4E);   // quad_perm [2,3,0,1]  == xor2
    x = DPP_ADD(x, 0x141);  // row_half_mirror (^7) == xor4 on quad-uniform
    x = DPP_ADD(x, 0x140);  // row_mirror (^15)     == xor8 on oct-uniform
    int y = __builtin_amdgcn_ds_swizzle(__builtin_bit_cast(int, x), 0x401F); // xor16 within 32
    return x + __builtin_bit_cast(float, y);
}

__device__ __forceinline__ float sigmoidf_(float x) {
    return 1.0f / (1.0f + __expf(-x));
}

__global__ __launch_bounds__(256, 2)
void reflex_fused(const float* __restrict__ obs,
                  const float* __restrict__ sw1, const float* __restrict__ sb1,
                  const float* __restrict__ sw2, const float* __restrict__ sb2,
                  const float* __restrict__ sw3, const float* __restrict__ sb3,
                  const float* __restrict__ rw1, const float* __restrict__ rb1,
                  const float* __restrict__ rw2, const float* __restrict__ rb2,
                  const float* __restrict__ am,  float* __restrict__ out)
{
    __shared__ __align__(16) float obs_s[BT * HSTR];
    __shared__ __align__(16) float lat_s[BT * 26];
    __shared__ __align__(16) union {
        struct { float h1[BT * HSTR]; float h2[BT * HSTR]; } p1;
        struct { float At[2][128 * ATS]; float Wt[2][128 * WTS]; } p2;
    } U;

    const int tid  = threadIdx.x;
    const int row0 = blockIdx.x * BT;

    // ---------------- Phase 1: supervisor (weights straight from L2) ----------------
    {   // stage obs tile: 1 float4 per thread
        const int r = tid >> 4, f = tid & 15;
        *(float4*)&obs_s[r * HSTR + f * 4] =
            *(const float4*)&obs[(row0 + r) * TOBS + f * 4];
    }
    __syncthreads();

    {   // layer 1: h1 = relu(obs @ sw1 + sb1); thread = (row, 4 cols)
        const int r = tid >> 4, j0 = (tid & 15) * 4;
        float4 acc = *(const float4*)&sb1[j0];
        #pragma unroll 8
        for (int k = 0; k < 64; ++k) {
            float x = obs_s[r * HSTR + k];
            const float4 w = *(const float4*)&sw1[k * 64 + j0];
            acc.x = fmaf(x, w.x, acc.x); acc.y = fmaf(x, w.y, acc.y);
            acc.z = fmaf(x, w.z, acc.z); acc.w = fmaf(x, w.w, acc.w);
        }
        *(float4*)&U.p1.h1[r * HSTR + j0] =
            make_float4(fmaxf(acc.x, 0.f), fmaxf(acc.y, 0.f),
                        fmaxf(acc.z, 0.f), fmaxf(acc.w, 0.f));
    }
    __syncthreads();

    {   // layer 2
        const int r = tid >> 4, j0 = (tid & 15) * 4;
        float4 acc = *(const float4*)&sb2[j0];
        #pragma unroll 8
        for (int k = 0; k < 64; ++k) {
            float x = U.p1.h1[r * HSTR + k];
            const float4 w = *(const float4*)&sw2[k * 64 + j0];
            acc.x = fmaf(x, w.x, acc.x); acc.y = fmaf(x, w.y, acc.y);
            acc.z = fmaf(x, w.z, acc.z); acc.w = fmaf(x, w.w, acc.w);
        }
        *(float4*)&U.p1.h2[r * HSTR + j0] =
            make_float4(fmaxf(acc.x, 0.f), fmaxf(acc.y, 0.f),
                        fmaxf(acc.z, 0.f), fmaxf(acc.w, 0.f));
    }
    __syncthreads();

    {   // layer 3: latent = sigmoid(h2 @ sw3 + sb3); thread = (row, 2 cols)
        const int r = tid >> 4, q = tid & 15;
        if (q < 13) {
            const int j = q * 2;
            float a0 = sb3[j];
            float a1 = (j + 1 < TLAT) ? sb3[j + 1] : 0.f;
            #pragma unroll 8
            for (int k = 0; k < 64; ++k) {
                float x = U.p1.h2[r * HSTR + k];
                a0 = fmaf(x, sw3[k * TLAT + j], a0);
                if (j + 1 < TLAT) a1 = fmaf(x, sw3[k * TLAT + j + 1], a1);
            }
            lat_s[r * 26 + j] = sigmoidf_(a0);
            if (j + 1 < TLAT) lat_s[r * 26 + j + 1] = sigmoidf_(a1);
        }
    }

    // ---------------- Phase 2: gating + reflex ----------------
    const int a  = tid & 31;
    const int hw = tid >> 5;
    const int r0 = hw * 2, r1 = r0 + 1;

    float pA[13], pW[8], pB2 = 0.f;

    auto stage_load = [&](int c) {
        const int o0 = c * OCH;
        const float* amc = am + o0 * TACT;          // am[l*2048 + o0*32 + jb]
        #pragma unroll
        for (int t = 0; t < 13; ++t) {
            int i = tid + t * 256;
            if (i < 3200) {
                int l = i >> 7, jb = i & 127;
                pA[t] = amc[l * (TOBS * TACT) + jb];
            }
        }
        const int base160 = o0 * 160;
        #pragma unroll
        for (int t = 0; t < 8; ++t) {
            int i = tid + t * 256;
            if (i < 1920) {
                int arr = i / 640, rem = i - arr * 640;
                const float* p = (arr == 0) ? rw1 : ((arr == 1) ? rb1 : rw2);
                pW[t] = p[base160 + rem];
            }
        }
        if (tid < 128) pB2 = rb2[o0 * TACT + tid];
    };

    auto stage_write = [&](int b) {
        float* Ab = U.p2.At[b];
        #pragma unroll
        for (int t = 0; t < 13; ++t) {
            int i = tid + t * 256;
            if (i < 3200) {
                int l = i >> 7, jb = i & 127;
                Ab[jb * ATS + l] = pA[t];
            }
        }
        float* Wb = U.p2.Wt[b];
        #pragma unroll
        for (int t = 0; t < 8; ++t) {
            int i = tid + t * 256;
            if (i < 1920) {
                int arr = i / 640, rem = i - arr * 640;
                int g = rem / 5, h = rem - g * 5;
                Wb[g * WTS + arr * 5 + h] = pW[t];
            }
        }
        if (tid < 128) Wb[tid * WTS + 15] = pB2;
    };

    stage_load(0);          // overlaps with other threads finishing phase 1
    __syncthreads();        // lat_s ready, h1/h2 region free
    float latA[TLAT], latB[TLAT];
    #pragma unroll
    for (int l = 0; l < TLAT; ++l) {
        latA[l] = lat_s[r0 * 26 + l];
        latB[l] = lat_s[r1 * 26 + l];
    }
    stage_write(0);
    __syncthreads();        // buf0 ready

    float acc0 = 0.f, acc1 = 0.f;

    for (int c = 0; c < NCH; ++c) {
        if (c + 1 < NCH) stage_load(c + 1);     // global -> regs, overlaps compute

        {   // compute chunk c from buf[c&1]
            const float* Ab = U.p2.At[c & 1];
            const float* Wb = U.p2.Wt[c & 1];
            #pragma unroll
            for (int oc = 0; oc < OCH; ++oc) {
                const int o  = c * OCH + oc;
                const int jb = oc * TACT + a;

                float Af[28];
                const float4* A4 = (const float4*)&Ab[jb * ATS];
                #pragma unroll
                for (int t = 0; t < 7; ++t) *(float4*)&Af[4 * t] = A4[t];

                float l0 = 0.f, l1 = 0.f;
                #pragma unroll
                for (int l = 0; l < TLAT; ++l) {
                    l0 = fmaf(Af[l], latA[l], l0);
                    l1 = fmaf(Af[l], latB[l], l1);
                }
                float e0 = __expf(l0), e1 = __expf(l1);
                float s0 = halfwave_sum(e0), s1 = halfwave_sum(e1);
                float p0 = e0 * __builtin_amdgcn_rcpf(s0);
                float p1 = e1 * __builtin_amdgcn_rcpf(s1);

                float wv[16];
                const float4* W4 = (const float4*)&Wb[jb * WTS];
                #pragma unroll
                for (int t = 0; t < 4; ++t) *(float4*)&wv[4 * t] = W4[t];

                float x0 = obs_s[r0 * HSTR + o], x1 = obs_s[r1 * HSTR + o];
                float ro0 = wv[15], ro1 = wv[15];
                #pragma unroll
                for (int h = 0; h < TH; ++h) {
                    float t0 = fmaxf(fmaf(x0, wv[h], wv[5 + h]), 0.f);
                    float t1 = fmaxf(fmaf(x1, wv[h], wv[5 + h]), 0.f);
                    ro0 = fmaf(t0, wv[10 + h], ro0);
                    ro1 = fmaf(t1, wv[10 + h], ro1);
                }
                acc0 = fmaf(ro0, p0, acc0);
                acc1 = fmaf(ro1, p1, acc1);
            }
        }

        if (c + 1 < NCH) {
            stage_write((c + 1) & 1);   // waits on its own vmcnt, after compute
            __syncthreads();
        }
    }

    out[(row0 + r0) * TACT + a] = acc0;
    out[(row0 + r1) * TACT + a] = acc1;
}

extern "C" void kernel_launch(void* const* d_in, const int* in_sizes, int n_in,
                              void* d_out, int out_size, void* d_ws, size_t ws_size,
                              hipStream_t stream) {
    const float* obs = (const float*)d_in[0];
    const float* sw1 = (const float*)d_in[1];
    const float* sb1 = (const float*)d_in[2];
    const float* sw2 = (const float*)d_in[3];
    const float* sb2 = (const float*)d_in[4];
    const float* sw3 = (const float*)d_in[5];
    const float* sb3 = (const float*)d_in[6];
    const float* rw1 = (const float*)d_in[7];
    const float* rb1 = (const float*)d_in[8];
    const float* rw2 = (const float*)d_in[9];
    const float* rb2 = (const float*)d_in[10];
    const float* am  = (const float*)d_in[11];
    float* out = (float*)d_out;

    reflex_fused<<<TB / BT, 256, 0, stream>>>(obs, sw1, sb1, sw2, sb2, sw3, sb3,
                                              rw1, rb1, rw2, rb2, am, out);
}

// Round 3
// 164.659 us; speedup vs baseline: 1.1491x; 1.1491x over previous
//
#include <hip/hip_runtime.h>

// ReflexPolicy fused v3: v1 structure + R=4 rows/thread with o-half split,
// DPP softmax, LDS<53.3KB for 3 blocks/CU. No stack arrays through casts.

#define TOBS 64
#define TACT 32
#define TLAT 25
#define TH   5
#define TB   8192
#define BT   16
#define NCH  8          // chunks of 8 o's (4 low-half + 4 high-half)
#define ATS  27         // At stride words (odd -> conflict-free b32)
#define WTS  17         // W stride words (odd)
#define HSTR 68

#define DPP_ADD(x, ctrl) \
  ((x) + __builtin_bit_cast(float, __builtin_amdgcn_update_dpp( \
      0, __builtin_bit_cast(int, (x)), (ctrl), 0xF, 0xF, true)))

__device__ __forceinline__ float halfwave_sum(float x) {
    x = DPP_ADD(x, 0xB1);   // xor1
    x = DPP_ADD(x, 0x4E);   // xor2
    x = DPP_ADD(x, 0x141);  // row_half_mirror == xor4
    x = DPP_ADD(x, 0x140);  // row_mirror      == xor8
    int y = __builtin_amdgcn_ds_swizzle(__builtin_bit_cast(int, x), 0x401F); // xor16
    return x + __builtin_bit_cast(float, y);
}

__device__ __forceinline__ float sigmoidf_(float x) {
    return 1.0f / (1.0f + __expf(-x));
}

__global__ __launch_bounds__(256, 3)
void reflex_fused(const float* __restrict__ obs,
                  const float* __restrict__ sw1, const float* __restrict__ sb1,
                  const float* __restrict__ sw2, const float* __restrict__ sb2,
                  const float* __restrict__ sw3, const float* __restrict__ sb3,
                  const float* __restrict__ rw1, const float* __restrict__ rb1,
                  const float* __restrict__ rw2, const float* __restrict__ rb2,
                  const float* __restrict__ am,  float* __restrict__ out)
{
    __shared__ __align__(16) float obs_s[BT * HSTR];
    __shared__ __align__(16) float lat_s[BT * 26];
    __shared__ __align__(16) union {
        struct { float h1[BT * HSTR]; float h2[BT * HSTR]; } p1;
        struct { float At[256 * ATS]; float W[256 * WTS]; } p2;
    } U;

    const int tid  = threadIdx.x;
    const int row0 = blockIdx.x * BT;

    // ---------------- Phase 1: supervisor (weights from L2) ----------------
    {
        const int r = tid >> 4, f = tid & 15;
        *(float4*)&obs_s[r * HSTR + f * 4] =
            *(const float4*)&obs[(row0 + r) * TOBS + f * 4];
    }
    __syncthreads();

    {   // layer 1
        const int r = tid >> 4, j0 = (tid & 15) * 4;
        float4 acc = *(const float4*)&sb1[j0];
        #pragma unroll 8
        for (int k = 0; k < 64; ++k) {
            float x = obs_s[r * HSTR + k];
            const float4 w = *(const float4*)&sw1[k * 64 + j0];
            acc.x = fmaf(x, w.x, acc.x); acc.y = fmaf(x, w.y, acc.y);
            acc.z = fmaf(x, w.z, acc.z); acc.w = fmaf(x, w.w, acc.w);
        }
        *(float4*)&U.p1.h1[r * HSTR + j0] =
            make_float4(fmaxf(acc.x, 0.f), fmaxf(acc.y, 0.f),
                        fmaxf(acc.z, 0.f), fmaxf(acc.w, 0.f));
    }
    __syncthreads();

    {   // layer 2
        const int r = tid >> 4, j0 = (tid & 15) * 4;
        float4 acc = *(const float4*)&sb2[j0];
        #pragma unroll 8
        for (int k = 0; k < 64; ++k) {
            float x = U.p1.h1[r * HSTR + k];
            const float4 w = *(const float4*)&sw2[k * 64 + j0];
            acc.x = fmaf(x, w.x, acc.x); acc.y = fmaf(x, w.y, acc.y);
            acc.z = fmaf(x, w.z, acc.z); acc.w = fmaf(x, w.w, acc.w);
        }
        *(float4*)&U.p1.h2[r * HSTR + j0] =
            make_float4(fmaxf(acc.x, 0.f), fmaxf(acc.y, 0.f),
                        fmaxf(acc.z, 0.f), fmaxf(acc.w, 0.f));
    }
    __syncthreads();

    {   // layer 3 -> lat_s
        const int r = tid >> 4, q = tid & 15;
        if (q < 13) {
            const int j = q * 2;
            float a0 = sb3[j];
            float a1 = (j + 1 < TLAT) ? sb3[j + 1] : 0.f;
            #pragma unroll 8
            for (int k = 0; k < 64; ++k) {
                float x = U.p1.h2[r * HSTR + k];
                a0 = fmaf(x, sw3[k * TLAT + j], a0);
                if (j + 1 < TLAT) a1 = fmaf(x, sw3[k * TLAT + j + 1], a1);
            }
            lat_s[r * 26 + j] = sigmoidf_(a0);
            if (j + 1 < TLAT) lat_s[r * 26 + j + 1] = sigmoidf_(a1);
        }
    }
    __syncthreads();   // lat_s ready; h1/h2 (union) dead

    // ---------------- Phase 2 ----------------
    const int a    = tid & 31;
    const int half = (tid >> 5) & 1;   // 0: o<32, 1: o>=32
    const int wid  = tid >> 6;         // wave id 0..3
    const int r0   = wid * 4;          // 4 rows per wave

    float lat0[TLAT], lat1[TLAT], lat2[TLAT], lat3[TLAT];
    #pragma unroll
    for (int l = 0; l < TLAT; ++l) {
        lat0[l] = lat_s[(r0 + 0) * 26 + l];
        lat1[l] = lat_s[(r0 + 1) * 26 + l];
        lat2[l] = lat_s[(r0 + 2) * 26 + l];
        lat3[l] = lat_s[(r0 + 3) * 26 + l];
    }

    // stage chunk c: 8 o's (4 per half), layout At[(s*32+a)*ATS + l], W[...*WTS + k]
    auto stage = [&](int c) {
        const int s  = tid >> 5, a_ = tid & 31;
        const int o  = c * 4 + ((s < 4) ? s : (28 + s));   // s>=4 -> 32 + c*4 + (s-4)
        const int ib = (s * 32 + a_);
        #pragma unroll
        for (int l = 0; l < TLAT; ++l)
            U.p2.At[ib * ATS + l] = am[(l * TOBS + o) * TACT + a_];
        const int gb = (o * TACT + a_) * TH;
        #pragma unroll
        for (int h = 0; h < TH; ++h) {
            U.p2.W[ib * WTS + h]      = rw1[gb + h];
            U.p2.W[ib * WTS + 5 + h]  = rb1[gb + h];
            U.p2.W[ib * WTS + 10 + h] = rw2[gb + h];
        }
        U.p2.W[ib * WTS + 15] = rb2[o * TACT + a_];
    };

    float acc0 = 0.f, acc1 = 0.f, acc2 = 0.f, acc3 = 0.f;

    stage(0);
    __syncthreads();

    for (int c = 0; c < NCH; ++c) {
        #pragma unroll
        for (int i = 0; i < 4; ++i) {
            const int slot = i + (half ? 4 : 0);
            const int o    = c * 4 + i + (half ? 32 : 0);
            const float* Ap = &U.p2.At[(slot * 32 + a) * ATS];

            float l0 = 0.f, l1 = 0.f, l2 = 0.f, l3 = 0.f;
            #pragma unroll
            for (int l = 0; l < TLAT; ++l) {
                float Av = Ap[l];
                l0 = fmaf(Av, lat0[l], l0);
                l1 = fmaf(Av, lat1[l], l1);
                l2 = fmaf(Av, lat2[l], l2);
                l3 = fmaf(Av, lat3[l], l3);
            }
            float e0 = __expf(l0), e1 = __expf(l1), e2 = __expf(l2), e3 = __expf(l3);
            float p0 = e0 * __builtin_amdgcn_rcpf(halfwave_sum(e0));
            float p1 = e1 * __builtin_amdgcn_rcpf(halfwave_sum(e1));
            float p2 = e2 * __builtin_amdgcn_rcpf(halfwave_sum(e2));
            float p3 = e3 * __builtin_amdgcn_rcpf(halfwave_sum(e3));

            const float* Wp = &U.p2.W[(slot * 32 + a) * WTS];
            float x0 = obs_s[(r0 + 0) * HSTR + o];
            float x1 = obs_s[(r0 + 1) * HSTR + o];
            float x2 = obs_s[(r0 + 2) * HSTR + o];
            float x3 = obs_s[(r0 + 3) * HSTR + o];
            float b2v = Wp[15];
            float ro0 = b2v, ro1 = b2v, ro2 = b2v, ro3 = b2v;
            #pragma unroll
            for (int h = 0; h < TH; ++h) {
                float w1v = Wp[h], b1v = Wp[5 + h], w2v = Wp[10 + h];
                ro0 = fmaf(fmaxf(fmaf(x0, w1v, b1v), 0.f), w2v, ro0);
                ro1 = fmaf(fmaxf(fmaf(x1, w1v, b1v), 0.f), w2v, ro1);
                ro2 = fmaf(fmaxf(fmaf(x2, w1v, b1v), 0.f), w2v, ro2);
                ro3 = fmaf(fmaxf(fmaf(x3, w1v, b1v), 0.f), w2v, ro3);
            }
            acc0 = fmaf(ro0, p0, acc0);
            acc1 = fmaf(ro1, p1, acc1);
            acc2 = fmaf(ro2, p2, acc2);
            acc3 = fmaf(ro3, p3, acc3);
        }
        if (c + 1 < NCH) {
            __syncthreads();
            stage(c + 1);
            __syncthreads();
        }
    }

    // combine o-halves (partner lane across the 32-boundary), then write
    acc0 += __shfl_xor(acc0, 32);
    acc1 += __shfl_xor(acc1, 32);
    acc2 += __shfl_xor(acc2, 32);
    acc3 += __shfl_xor(acc3, 32);

    const int  rw = r0 + half * 2;
    const float wA = half ? acc2 : acc0;
    const float wB = half ? acc3 : acc1;
    out[(row0 + rw)     * TACT + a] = wA;
    out[(row0 + rw + 1) * TACT + a] = wB;
}

extern "C" void kernel_launch(void* const* d_in, const int* in_sizes, int n_in,
                              void* d_out, int out_size, void* d_ws, size_t ws_size,
                              hipStream_t stream) {
    const float* obs = (const float*)d_in[0];
    const float* sw1 = (const float*)d_in[1];
    const float* sb1 = (const float*)d_in[2];
    const float* sw2 = (const float*)d_in[3];
    const float* sb2 = (const float*)d_in[4];
    const float* sw3 = (const float*)d_in[5];
    const float* sb3 = (const float*)d_in[6];
    const float* rw1 = (const float*)d_in[7];
    const float* rb1 = (const float*)d_in[8];
    const float* rw2 = (const float*)d_in[9];
    const float* rb2 = (const float*)d_in[10];
    const float* am  = (const float*)d_in[11];
    float* out = (float*)d_out;

    reflex_fused<<<TB / BT, 256, 0, stream>>>(obs, sw1, sb1, sw2, sb2, sw3, sb3,
                                              rw1, rb1, rw2, rb2, am, out);
}

// Round 4
// 151.060 us; speedup vs baseline: 1.2525x; 1.0900x over previous
//
#include <hip/hip_runtime.h>

// ReflexPolicy fused v4: v1 mapping (2 rows/thread), b128 LDS reads via NAMED
// float4s, DPP softmax, 4-o chunks -> 30.6KB LDS -> 4 blocks/CU.

#define TOBS 64
#define TACT 32
#define TLAT 25
#define TH   5
#define TB   8192
#define BT   16
#define NCH  16         // chunks of 4 o's
#define ATS  28         // At stride words (25 data + 3 pad)
#define WTS  20         // W stride words (16 data + 4 pad)
#define HSTR 68

#define DPP_ADD(x, ctrl) \
  ((x) + __builtin_bit_cast(float, __builtin_amdgcn_update_dpp( \
      0, __builtin_bit_cast(int, (x)), (ctrl), 0xF, 0xF, true)))

__device__ __forceinline__ float halfwave_sum(float x) {
    x = DPP_ADD(x, 0xB1);   // xor1
    x = DPP_ADD(x, 0x4E);   // xor2
    x = DPP_ADD(x, 0x141);  // row_half_mirror == xor4
    x = DPP_ADD(x, 0x140);  // row_mirror      == xor8
    int y = __builtin_amdgcn_ds_swizzle(__builtin_bit_cast(int, x), 0x401F); // xor16
    return x + __builtin_bit_cast(float, y);
}

__device__ __forceinline__ float sigmoidf_(float x) {
    return 1.0f / (1.0f + __expf(-x));
}

__global__ __launch_bounds__(256, 4)
void reflex_fused(const float* __restrict__ obs,
                  const float* __restrict__ sw1, const float* __restrict__ sb1,
                  const float* __restrict__ sw2, const float* __restrict__ sb2,
                  const float* __restrict__ sw3, const float* __restrict__ sb3,
                  const float* __restrict__ rw1, const float* __restrict__ rb1,
                  const float* __restrict__ rw2, const float* __restrict__ rb2,
                  const float* __restrict__ am,  float* __restrict__ out)
{
    __shared__ __align__(16) float obs_s[BT * HSTR];
    __shared__ __align__(16) float lat_s[BT * 26];
    __shared__ __align__(16) union {
        struct { float h1[BT * HSTR]; float h2[BT * HSTR]; } p1;
        struct { float At[128 * ATS]; float W[128 * WTS]; } p2;
    } U;

    const int tid  = threadIdx.x;
    const int row0 = blockIdx.x * BT;

    // ---------------- Phase 1: supervisor (weights from L2) ----------------
    {
        const int r = tid >> 4, f = tid & 15;
        *(float4*)&obs_s[r * HSTR + f * 4] =
            *(const float4*)&obs[(row0 + r) * TOBS + f * 4];
    }
    __syncthreads();

    {   // layer 1
        const int r = tid >> 4, j0 = (tid & 15) * 4;
        float4 acc = *(const float4*)&sb1[j0];
        #pragma unroll 8
        for (int k = 0; k < 64; ++k) {
            float x = obs_s[r * HSTR + k];
            const float4 w = *(const float4*)&sw1[k * 64 + j0];
            acc.x = fmaf(x, w.x, acc.x); acc.y = fmaf(x, w.y, acc.y);
            acc.z = fmaf(x, w.z, acc.z); acc.w = fmaf(x, w.w, acc.w);
        }
        *(float4*)&U.p1.h1[r * HSTR + j0] =
            make_float4(fmaxf(acc.x, 0.f), fmaxf(acc.y, 0.f),
                        fmaxf(acc.z, 0.f), fmaxf(acc.w, 0.f));
    }
    __syncthreads();

    {   // layer 2
        const int r = tid >> 4, j0 = (tid & 15) * 4;
        float4 acc = *(const float4*)&sb2[j0];
        #pragma unroll 8
        for (int k = 0; k < 64; ++k) {
            float x = U.p1.h1[r * HSTR + k];
            const float4 w = *(const float4*)&sw2[k * 64 + j0];
            acc.x = fmaf(x, w.x, acc.x); acc.y = fmaf(x, w.y, acc.y);
            acc.z = fmaf(x, w.z, acc.z); acc.w = fmaf(x, w.w, acc.w);
        }
        *(float4*)&U.p1.h2[r * HSTR + j0] =
            make_float4(fmaxf(acc.x, 0.f), fmaxf(acc.y, 0.f),
                        fmaxf(acc.z, 0.f), fmaxf(acc.w, 0.f));
    }
    __syncthreads();

    {   // layer 3 -> lat_s
        const int r = tid >> 4, q = tid & 15;
        if (q < 13) {
            const int j = q * 2;
            float a0 = sb3[j];
            float a1 = (j + 1 < TLAT) ? sb3[j + 1] : 0.f;
            #pragma unroll 8
            for (int k = 0; k < 64; ++k) {
                float x = U.p1.h2[r * HSTR + k];
                a0 = fmaf(x, sw3[k * TLAT + j], a0);
                if (j + 1 < TLAT) a1 = fmaf(x, sw3[k * TLAT + j + 1], a1);
            }
            lat_s[r * 26 + j] = sigmoidf_(a0);
            if (j + 1 < TLAT) lat_s[r * 26 + j + 1] = sigmoidf_(a1);
        }
    }
    __syncthreads();   // lat_s ready; h1/h2 (union) dead

    // ---------------- Phase 2 ----------------
    const int a  = tid & 31;
    const int hw = tid >> 5;        // 0..7 half-wave id
    const int r0 = hw * 2, r1 = r0 + 1;

    float latA[TLAT], latB[TLAT];
    #pragma unroll
    for (int l = 0; l < TLAT; ++l) {
        latA[l] = lat_s[r0 * 26 + l];
        latB[l] = lat_s[r1 * 26 + l];
    }

    // stage chunk c (4 o's). Threads 0..127 stage At, 128..255 stage W.
    auto stage = [&](int c) {
        if (tid < 128) {
            const int slot = tid >> 5, a_ = tid & 31;
            const int o = c * 4 + slot;
            const float* g = am + o * TACT + a_;           // stride 2048 over l
            float v0  = g[0*2048],  v1  = g[1*2048],  v2  = g[2*2048],  v3  = g[3*2048];
            float v4  = g[4*2048],  v5  = g[5*2048],  v6  = g[6*2048],  v7  = g[7*2048];
            float v8  = g[8*2048],  v9  = g[9*2048],  v10 = g[10*2048], v11 = g[11*2048];
            float v12 = g[12*2048], v13 = g[13*2048], v14 = g[14*2048], v15 = g[15*2048];
            float v16 = g[16*2048], v17 = g[17*2048], v18 = g[18*2048], v19 = g[19*2048];
            float v20 = g[20*2048], v21 = g[21*2048], v22 = g[22*2048], v23 = g[23*2048];
            float v24 = g[24*2048];
            float* d = &U.p2.At[tid * ATS];
            ((float4*)d)[0] = make_float4(v0,  v1,  v2,  v3);
            ((float4*)d)[1] = make_float4(v4,  v5,  v6,  v7);
            ((float4*)d)[2] = make_float4(v8,  v9,  v10, v11);
            ((float4*)d)[3] = make_float4(v12, v13, v14, v15);
            ((float4*)d)[4] = make_float4(v16, v17, v18, v19);
            ((float4*)d)[5] = make_float4(v20, v21, v22, v23);
            d[24] = v24;
        } else {
            const int t = tid - 128;
            const int slot = t >> 5, a_ = t & 31;
            const int o = c * 4 + slot;
            const int gb = (o * TACT + a_) * TH;
            float w10 = rw1[gb], w11 = rw1[gb+1], w12 = rw1[gb+2], w13 = rw1[gb+3], w14 = rw1[gb+4];
            float b10 = rb1[gb], b11 = rb1[gb+1], b12 = rb1[gb+2], b13 = rb1[gb+3], b14 = rb1[gb+4];
            float w20 = rw2[gb], w21 = rw2[gb+1], w22 = rw2[gb+2], w23 = rw2[gb+3], w24 = rw2[gb+4];
            float b2v = rb2[o * TACT + a_];
            float* d = &U.p2.W[t * WTS];
            ((float4*)d)[0] = make_float4(w10, w11, w12, w13);
            ((float4*)d)[1] = make_float4(w14, b10, b11, b12);
            ((float4*)d)[2] = make_float4(b13, b14, w20, w21);
            ((float4*)d)[3] = make_float4(w22, w23, w24, b2v);
        }
    };

    float acc0 = 0.f, acc1 = 0.f;

    stage(0);
    __syncthreads();

    for (int c = 0; c < NCH; ++c) {
        #pragma unroll
        for (int i = 0; i < 4; ++i) {
            const int o  = c * 4 + i;
            const float* Ap = &U.p2.At[(i * 32 + a) * ATS];
            const float4 A0 = ((const float4*)Ap)[0];
            const float4 A1 = ((const float4*)Ap)[1];
            const float4 A2 = ((const float4*)Ap)[2];
            const float4 A3 = ((const float4*)Ap)[3];
            const float4 A4 = ((const float4*)Ap)[4];
            const float4 A5 = ((const float4*)Ap)[5];
            const float  a24 = Ap[24];

            float l0 = 0.f, l1 = 0.f;
            #define DOT_(comp, idx) \
                l0 = fmaf((comp), latA[idx], l0); l1 = fmaf((comp), latB[idx], l1);
            DOT_(A0.x, 0)  DOT_(A0.y, 1)  DOT_(A0.z, 2)  DOT_(A0.w, 3)
            DOT_(A1.x, 4)  DOT_(A1.y, 5)  DOT_(A1.z, 6)  DOT_(A1.w, 7)
            DOT_(A2.x, 8)  DOT_(A2.y, 9)  DOT_(A2.z, 10) DOT_(A2.w, 11)
            DOT_(A3.x, 12) DOT_(A3.y, 13) DOT_(A3.z, 14) DOT_(A3.w, 15)
            DOT_(A4.x, 16) DOT_(A4.y, 17) DOT_(A4.z, 18) DOT_(A4.w, 19)
            DOT_(A5.x, 20) DOT_(A5.y, 21) DOT_(A5.z, 22) DOT_(A5.w, 23)
            DOT_(a24, 24)
            #undef DOT_

            float e0 = __expf(l0), e1 = __expf(l1);
            float p0 = e0 * __builtin_amdgcn_rcpf(halfwave_sum(e0));
            float p1 = e1 * __builtin_amdgcn_rcpf(halfwave_sum(e1));

            const float* Wp = &U.p2.W[(i * 32 + a) * WTS];
            const float4 W0 = ((const float4*)Wp)[0];
            const float4 W1 = ((const float4*)Wp)[1];
            const float4 W2 = ((const float4*)Wp)[2];
            const float4 W3 = ((const float4*)Wp)[3];

            float x0 = obs_s[r0 * HSTR + o], x1 = obs_s[r1 * HSTR + o];
            float ro0 = W3.w, ro1 = W3.w;
            // h: w1 = {W0.x,W0.y,W0.z,W0.w,W1.x}, b1 = {W1.y,W1.z,W1.w,W2.x,W2.y},
            //    w2 = {W2.z,W2.w,W3.x,W3.y,W3.z}, b2 = W3.w
            ro0 = fmaf(fmaxf(fmaf(x0, W0.x, W1.y), 0.f), W2.z, ro0);
            ro1 = fmaf(fmaxf(fmaf(x1, W0.x, W1.y), 0.f), W2.z, ro1);
            ro0 = fmaf(fmaxf(fmaf(x0, W0.y, W1.z), 0.f), W2.w, ro0);
            ro1 = fmaf(fmaxf(fmaf(x1, W0.y, W1.z), 0.f), W2.w, ro1);
            ro0 = fmaf(fmaxf(fmaf(x0, W0.z, W1.w), 0.f), W3.x, ro0);
            ro1 = fmaf(fmaxf(fmaf(x1, W0.z, W1.w), 0.f), W3.x, ro1);
            ro0 = fmaf(fmaxf(fmaf(x0, W0.w, W2.x), 0.f), W3.y, ro0);
            ro1 = fmaf(fmaxf(fmaf(x1, W0.w, W2.x), 0.f), W3.y, ro1);
            ro0 = fmaf(fmaxf(fmaf(x0, W1.x, W2.y), 0.f), W3.z, ro0);
            ro1 = fmaf(fmaxf(fmaf(x1, W1.x, W2.y), 0.f), W3.z, ro1);

            acc0 = fmaf(ro0, p0, acc0);
            acc1 = fmaf(ro1, p1, acc1);
        }
        if (c + 1 < NCH) {
            __syncthreads();
            stage(c + 1);
            __syncthreads();
        }
    }

    out[(row0 + r0) * TACT + a] = acc0;
    out[(row0 + r1) * TACT + a] = acc1;
}

extern "C" void kernel_launch(void* const* d_in, const int* in_sizes, int n_in,
                              void* d_out, int out_size, void* d_ws, size_t ws_size,
                              hipStream_t stream) {
    const float* obs = (const float*)d_in[0];
    const float* sw1 = (const float*)d_in[1];
    const float* sb1 = (const float*)d_in[2];
    const float* sw2 = (const float*)d_in[3];
    const float* sb2 = (const float*)d_in[4];
    const float* sw3 = (const float*)d_in[5];
    const float* sb3 = (const float*)d_in[6];
    const float* rw1 = (const float*)d_in[7];
    const float* rb1 = (const float*)d_in[8];
    const float* rw2 = (const float*)d_in[9];
    const float* rb2 = (const float*)d_in[10];
    const float* am  = (const float*)d_in[11];
    float* out = (float*)d_out;

    reflex_fused<<<TB / BT, 256, 0, stream>>>(obs, sw1, sb1, sw2, sb2, sw3, sb3,
                                              rw1, rb1, rw2, rb2, am, out);
}

// Round 5
// 53.584 us; speedup vs baseline: 3.5309x; 2.8191x over previous
//
#include <hip/hip_runtime.h>

// ReflexPolicy fused v5 = v4 structure with the register budget fixed:
// __launch_bounds__(256,2) (cap 128; v4's (256,4) capped at 64 -> spills),
// plus double-buffered At/W staging (one barrier per chunk).

#define TOBS 64
#define TACT 32
#define TLAT 25
#define TH   5
#define TB   8192
#define BT   16
#define NCH  16         // chunks of 4 o's
#define ATS  28         // At stride words (25 data + 3 pad)
#define WTS  20         // W stride words (16 data + 4 pad)
#define HSTR 68

#define DPP_ADD(x, ctrl) \
  ((x) + __builtin_bit_cast(float, __builtin_amdgcn_update_dpp( \
      0, __builtin_bit_cast(int, (x)), (ctrl), 0xF, 0xF, true)))

__device__ __forceinline__ float halfwave_sum(float x) {
    x = DPP_ADD(x, 0xB1);   // xor1
    x = DPP_ADD(x, 0x4E);   // xor2
    x = DPP_ADD(x, 0x141);  // row_half_mirror == xor4
    x = DPP_ADD(x, 0x140);  // row_mirror      == xor8
    int y = __builtin_amdgcn_ds_swizzle(__builtin_bit_cast(int, x), 0x401F); // xor16
    return x + __builtin_bit_cast(float, y);
}

__device__ __forceinline__ float sigmoidf_(float x) {
    return 1.0f / (1.0f + __expf(-x));
}

__global__ __launch_bounds__(256, 2)
void reflex_fused(const float* __restrict__ obs,
                  const float* __restrict__ sw1, const float* __restrict__ sb1,
                  const float* __restrict__ sw2, const float* __restrict__ sb2,
                  const float* __restrict__ sw3, const float* __restrict__ sb3,
                  const float* __restrict__ rw1, const float* __restrict__ rb1,
                  const float* __restrict__ rw2, const float* __restrict__ rb2,
                  const float* __restrict__ am,  float* __restrict__ out)
{
    __shared__ __align__(16) float obs_s[BT * HSTR];
    __shared__ __align__(16) float lat_s[BT * 26];
    __shared__ __align__(16) union {
        struct { float h1[BT * HSTR]; float h2[BT * HSTR]; } p1;
        struct { float At[2][128 * ATS]; float W[2][128 * WTS]; } p2;
    } U;

    const int tid  = threadIdx.x;
    const int row0 = blockIdx.x * BT;

    // ---------------- Phase 1: supervisor (weights from L2) ----------------
    {
        const int r = tid >> 4, f = tid & 15;
        *(float4*)&obs_s[r * HSTR + f * 4] =
            *(const float4*)&obs[(row0 + r) * TOBS + f * 4];
    }
    __syncthreads();

    {   // layer 1
        const int r = tid >> 4, j0 = (tid & 15) * 4;
        float4 acc = *(const float4*)&sb1[j0];
        #pragma unroll 8
        for (int k = 0; k < 64; ++k) {
            float x = obs_s[r * HSTR + k];
            const float4 w = *(const float4*)&sw1[k * 64 + j0];
            acc.x = fmaf(x, w.x, acc.x); acc.y = fmaf(x, w.y, acc.y);
            acc.z = fmaf(x, w.z, acc.z); acc.w = fmaf(x, w.w, acc.w);
        }
        *(float4*)&U.p1.h1[r * HSTR + j0] =
            make_float4(fmaxf(acc.x, 0.f), fmaxf(acc.y, 0.f),
                        fmaxf(acc.z, 0.f), fmaxf(acc.w, 0.f));
    }
    __syncthreads();

    {   // layer 2
        const int r = tid >> 4, j0 = (tid & 15) * 4;
        float4 acc = *(const float4*)&sb2[j0];
        #pragma unroll 8
        for (int k = 0; k < 64; ++k) {
            float x = U.p1.h1[r * HSTR + k];
            const float4 w = *(const float4*)&sw2[k * 64 + j0];
            acc.x = fmaf(x, w.x, acc.x); acc.y = fmaf(x, w.y, acc.y);
            acc.z = fmaf(x, w.z, acc.z); acc.w = fmaf(x, w.w, acc.w);
        }
        *(float4*)&U.p1.h2[r * HSTR + j0] =
            make_float4(fmaxf(acc.x, 0.f), fmaxf(acc.y, 0.f),
                        fmaxf(acc.z, 0.f), fmaxf(acc.w, 0.f));
    }
    __syncthreads();

    {   // layer 3 -> lat_s
        const int r = tid >> 4, q = tid & 15;
        if (q < 13) {
            const int j = q * 2;
            float a0 = sb3[j];
            float a1 = (j + 1 < TLAT) ? sb3[j + 1] : 0.f;
            #pragma unroll 8
            for (int k = 0; k < 64; ++k) {
                float x = U.p1.h2[r * HSTR + k];
                a0 = fmaf(x, sw3[k * TLAT + j], a0);
                if (j + 1 < TLAT) a1 = fmaf(x, sw3[k * TLAT + j + 1], a1);
            }
            lat_s[r * 26 + j] = sigmoidf_(a0);
            if (j + 1 < TLAT) lat_s[r * 26 + j + 1] = sigmoidf_(a1);
        }
    }
    __syncthreads();   // lat_s ready; h1/h2 (union) dead

    // ---------------- Phase 2 ----------------
    const int a  = tid & 31;
    const int hw = tid >> 5;        // 0..7 half-wave id
    const int r0 = hw * 2, r1 = r0 + 1;

    float latA[TLAT], latB[TLAT];
    #pragma unroll
    for (int l = 0; l < TLAT; ++l) {
        latA[l] = lat_s[r0 * 26 + l];
        latB[l] = lat_s[r1 * 26 + l];
    }

    // stage chunk c (4 o's) into buffer b. Threads 0..127: At, 128..255: W.
    auto stage = [&](int c, int b) {
        if (tid < 128) {
            const int slot = tid >> 5, a_ = tid & 31;
            const int o = c * 4 + slot;
            const float* g = am + o * TACT + a_;           // stride 2048 over l
            float v0  = g[0*2048],  v1  = g[1*2048],  v2  = g[2*2048],  v3  = g[3*2048];
            float v4  = g[4*2048],  v5  = g[5*2048],  v6  = g[6*2048],  v7  = g[7*2048];
            float v8  = g[8*2048],  v9  = g[9*2048],  v10 = g[10*2048], v11 = g[11*2048];
            float v12 = g[12*2048], v13 = g[13*2048], v14 = g[14*2048], v15 = g[15*2048];
            float v16 = g[16*2048], v17 = g[17*2048], v18 = g[18*2048], v19 = g[19*2048];
            float v20 = g[20*2048], v21 = g[21*2048], v22 = g[22*2048], v23 = g[23*2048];
            float v24 = g[24*2048];
            float* d = &U.p2.At[b][tid * ATS];
            ((float4*)d)[0] = make_float4(v0,  v1,  v2,  v3);
            ((float4*)d)[1] = make_float4(v4,  v5,  v6,  v7);
            ((float4*)d)[2] = make_float4(v8,  v9,  v10, v11);
            ((float4*)d)[3] = make_float4(v12, v13, v14, v15);
            ((float4*)d)[4] = make_float4(v16, v17, v18, v19);
            ((float4*)d)[5] = make_float4(v20, v21, v22, v23);
            d[24] = v24;
        } else {
            const int t = tid - 128;
            const int slot = t >> 5, a_ = t & 31;
            const int o = c * 4 + slot;
            const int gb = (o * TACT + a_) * TH;
            float w10 = rw1[gb], w11 = rw1[gb+1], w12 = rw1[gb+2], w13 = rw1[gb+3], w14 = rw1[gb+4];
            float b10 = rb1[gb], b11 = rb1[gb+1], b12 = rb1[gb+2], b13 = rb1[gb+3], b14 = rb1[gb+4];
            float w20 = rw2[gb], w21 = rw2[gb+1], w22 = rw2[gb+2], w23 = rw2[gb+3], w24 = rw2[gb+4];
            float b2v = rb2[o * TACT + a_];
            float* d = &U.p2.W[b][t * WTS];
            ((float4*)d)[0] = make_float4(w10, w11, w12, w13);
            ((float4*)d)[1] = make_float4(w14, b10, b11, b12);
            ((float4*)d)[2] = make_float4(b13, b14, w20, w21);
            ((float4*)d)[3] = make_float4(w22, w23, w24, b2v);
        }
    };

    float acc0 = 0.f, acc1 = 0.f;

    stage(0, 0);
    __syncthreads();

    for (int c = 0; c < NCH; ++c) {
        const float* Atb = U.p2.At[c & 1];
        const float* Wb  = U.p2.W[c & 1];
        #pragma unroll
        for (int i = 0; i < 4; ++i) {
            const int o  = c * 4 + i;
            const float* Ap = &Atb[(i * 32 + a) * ATS];
            const float4 A0 = ((const float4*)Ap)[0];
            const float4 A1 = ((const float4*)Ap)[1];
            const float4 A2 = ((const float4*)Ap)[2];
            const float4 A3 = ((const float4*)Ap)[3];
            const float4 A4 = ((const float4*)Ap)[4];
            const float4 A5 = ((const float4*)Ap)[5];
            const float  a24 = Ap[24];

            float l0 = 0.f, l1 = 0.f;
            #define DOT_(comp, idx) \
                l0 = fmaf((comp), latA[idx], l0); l1 = fmaf((comp), latB[idx], l1);
            DOT_(A0.x, 0)  DOT_(A0.y, 1)  DOT_(A0.z, 2)  DOT_(A0.w, 3)
            DOT_(A1.x, 4)  DOT_(A1.y, 5)  DOT_(A1.z, 6)  DOT_(A1.w, 7)
            DOT_(A2.x, 8)  DOT_(A2.y, 9)  DOT_(A2.z, 10) DOT_(A2.w, 11)
            DOT_(A3.x, 12) DOT_(A3.y, 13) DOT_(A3.z, 14) DOT_(A3.w, 15)
            DOT_(A4.x, 16) DOT_(A4.y, 17) DOT_(A4.z, 18) DOT_(A4.w, 19)
            DOT_(A5.x, 20) DOT_(A5.y, 21) DOT_(A5.z, 22) DOT_(A5.w, 23)
            DOT_(a24, 24)
            #undef DOT_

            float e0 = __expf(l0), e1 = __expf(l1);
            float p0 = e0 * __builtin_amdgcn_rcpf(halfwave_sum(e0));
            float p1 = e1 * __builtin_amdgcn_rcpf(halfwave_sum(e1));

            const float* Wp = &Wb[(i * 32 + a) * WTS];
            const float4 W0 = ((const float4*)Wp)[0];
            const float4 W1 = ((const float4*)Wp)[1];
            const float4 W2 = ((const float4*)Wp)[2];
            const float4 W3 = ((const float4*)Wp)[3];

            float x0 = obs_s[r0 * HSTR + o], x1 = obs_s[r1 * HSTR + o];
            float ro0 = W3.w, ro1 = W3.w;
            // w1 = {W0.x..W0.w,W1.x}, b1 = {W1.y..W1.w,W2.x,W2.y},
            // w2 = {W2.z,W2.w,W3.x,W3.y,W3.z}, b2 = W3.w
            ro0 = fmaf(fmaxf(fmaf(x0, W0.x, W1.y), 0.f), W2.z, ro0);
            ro1 = fmaf(fmaxf(fmaf(x1, W0.x, W1.y), 0.f), W2.z, ro1);
            ro0 = fmaf(fmaxf(fmaf(x0, W0.y, W1.z), 0.f), W2.w, ro0);
            ro1 = fmaf(fmaxf(fmaf(x1, W0.y, W1.z), 0.f), W2.w, ro1);
            ro0 = fmaf(fmaxf(fmaf(x0, W0.z, W1.w), 0.f), W3.x, ro0);
            ro1 = fmaf(fmaxf(fmaf(x1, W0.z, W1.w), 0.f), W3.x, ro1);
            ro0 = fmaf(fmaxf(fmaf(x0, W0.w, W2.x), 0.f), W3.y, ro0);
            ro1 = fmaf(fmaxf(fmaf(x1, W0.w, W2.x), 0.f), W3.y, ro1);
            ro0 = fmaf(fmaxf(fmaf(x0, W1.x, W2.y), 0.f), W3.z, ro0);
            ro1 = fmaf(fmaxf(fmaf(x1, W1.x, W2.y), 0.f), W3.z, ro1);

            acc0 = fmaf(ro0, p0, acc0);
            acc1 = fmaf(ro1, p1, acc1);
        }
        if (c + 1 < NCH) stage(c + 1, (c + 1) & 1);  // writes the idle buffer
        __syncthreads();
    }

    out[(row0 + r0) * TACT + a] = acc0;
    out[(row0 + r1) * TACT + a] = acc1;
}

extern "C" void kernel_launch(void* const* d_in, const int* in_sizes, int n_in,
                              void* d_out, int out_size, void* d_ws, size_t ws_size,
                              hipStream_t stream) {
    const float* obs = (const float*)d_in[0];
    const float* sw1 = (const float*)d_in[1];
    const float* sb1 = (const float*)d_in[2];
    const float* sw2 = (const float*)d_in[3];
    const float* sb2 = (const float*)d_in[4];
    const float* sw3 = (const float*)d_in[5];
    const float* sb3 = (const float*)d_in[6];
    const float* rw1 = (const float*)d_in[7];
    const float* rb1 = (const float*)d_in[8];
    const float* rw2 = (const float*)d_in[9];
    const float* rb2 = (const float*)d_in[10];
    const float* am  = (const float*)d_in[11];
    float* out = (float*)d_out;

    reflex_fused<<<TB / BT, 256, 0, stream>>>(obs, sw1, sb1, sw2, sb2, sw3, sb3,
                                              rw1, rb1, rw2, rb2, am, out);
}